// Round 13
// baseline (205.038 us; speedup 1.0000x reference)
//
#include <hip/hip_runtime.h>
#include <math.h>

#define NN 20000
#define NE 320000
#define NG 128

typedef short short8 __attribute__((ext_vector_type(8)));
typedef float f32x4 __attribute__((ext_vector_type(4)));
typedef float f32x2 __attribute__((ext_vector_type(2)));
typedef unsigned short ushort;
typedef unsigned short ushort4v __attribute__((ext_vector_type(4)));
typedef float float4v __attribute__((ext_vector_type(4)));
typedef unsigned int uint;
typedef unsigned int uint2v __attribute__((ext_vector_type(2)));

__device__ __forceinline__ float b2f(ushort u) {
    unsigned int v = ((unsigned int)u) << 16;
    return __uint_as_float(v);
}
__device__ __forceinline__ ushort f2b(float f) {
    unsigned int u = __float_as_uint(f);
    u = (u + 0x7fff + ((u >> 16) & 1)) >> 16;   // RNE
    return (ushort)u;
}
__device__ __forceinline__ float lrelu(float x) { return x >= 0.f ? x : 0.2f * x; }
__device__ __forceinline__ unsigned char f2f8(float v) {
    return (unsigned char)(__builtin_amdgcn_cvt_pk_fp8_f32(v, v, 0, false) & 0xff);
}
// decode 8 fp8 bytes (uint2v) -> 4 packed f32x2 (literal word selects)
__device__ __forceinline__ void dec8(uint2v r, f32x2 d[4]) {
    d[0] = __builtin_amdgcn_cvt_pk_f32_fp8(r.x, false);
    d[1] = __builtin_amdgcn_cvt_pk_f32_fp8(r.x, true);
    d[2] = __builtin_amdgcn_cvt_pk_f32_fp8(r.y, false);
    d[3] = __builtin_amdgcn_cvt_pk_f32_fp8(r.y, true);
}

// ---------------------------------------------------------------------------
// fused f32->bf16 convert of x, W1, W2, W3 + edge-dst counting (one launch)
// ---------------------------------------------------------------------------
#define CVT_N0 (NN * 64 / 4)
#define CVT_N1 (320 * 64 / 4)
#define CVT_N2 (480 * 320 / 4)
#define CVT_N3 (32 * 480 / 4)
#define CVT_TOT (CVT_N0 + CVT_N1 + CVT_N2 + CVT_N3)
__global__ void cvt_count_kernel(const float* __restrict__ a0, ushort* __restrict__ o0,
                                 const float* __restrict__ a1, ushort* __restrict__ o1,
                                 const float* __restrict__ a2, ushort* __restrict__ o2,
                                 const float* __restrict__ a3, ushort* __restrict__ o3,
                                 const int* __restrict__ e_dst, int* __restrict__ cnt, int E) {
    int i = blockIdx.x * blockDim.x + threadIdx.x;
    if (i < E) atomicAdd(&cnt[e_dst[i]], 1);
    const float* src; ushort* dst; int li;
    if (i < CVT_N0) { src = a0; dst = o0; li = i; }
    else if (i < CVT_N0 + CVT_N1) { src = a1; dst = o1; li = i - CVT_N0; }
    else if (i < CVT_N0 + CVT_N1 + CVT_N2) { src = a2; dst = o2; li = i - CVT_N0 - CVT_N1; }
    else if (i < CVT_TOT) { src = a3; dst = o3; li = i - CVT_N0 - CVT_N1 - CVT_N2; }
    else return;
    float4v v = *(const float4v*)(src + (size_t)li * 4);
    ushort4v r;
    r.x = f2b(v.x); r.y = f2b(v.y); r.z = f2b(v.z); r.w = f2b(v.w);
    *(ushort4v*)(dst + (size_t)li * 4) = r;
}

// ---------------------------------------------------------------------------
// CSR build: (count fused above) -> parallel scan -> fill
// ---------------------------------------------------------------------------
__global__ __launch_bounds__(1024) void scan_kernel(const int* __restrict__ cnt,
                                                    int* __restrict__ row_start, int n) {
    __shared__ int sh[1024];
    int tid = threadIdx.x;
    int base = tid * 20;
    int local[20];
    int s = 0;
    #pragma unroll
    for (int k = 0; k < 20; ++k) {
        int idx = base + k;
        int v = (idx < n) ? cnt[idx] : 0;
        local[k] = s;           // exclusive within chunk
        s += v;
    }
    sh[tid] = s;
    __syncthreads();
    for (int off = 1; off < 1024; off <<= 1) {
        int t = (tid >= off) ? sh[tid - off] : 0;
        __syncthreads();
        sh[tid] += t;
        __syncthreads();
    }
    int pre = (tid == 0) ? 0 : sh[tid - 1];
    #pragma unroll
    for (int k = 0; k < 20; ++k) {
        int idx = base + k;
        if (idx < n) row_start[idx] = pre + local[k];
    }
    if (tid == 1023) row_start[n] = sh[1023];
}

__global__ void fill_kernel(const int* __restrict__ src, const int* __restrict__ dst,
                            const int* __restrict__ row_start, int* __restrict__ cursor,
                            int* __restrict__ csr_src, int E) {
    int i = blockIdx.x * blockDim.x + threadIdx.x;
    if (i < E) {
        int d = dst[i];
        int pos = atomicAdd(&cursor[d], 1);
        csr_src[row_start[d] + pos] = src[i];
    }
}

// ---------------------------------------------------------------------------
// MFMA GEMM, K-chunked LDS staging (chunk KC<=160 -> small LDS, high occ) +
// reg double-buffering + FUSED per-head attention dots (BN == C, head = bx).
// F8 variant stores C as fp8 e4m3 bytes (direct from f32 acc).
// ---------------------------------------------------------------------------
template <int K, int NF, int H, bool F8>
__global__ __launch_bounds__(256) void gemm_lds(const ushort* __restrict__ A,
                                                const ushort* __restrict__ B,
                                                ushort* __restrict__ C,
                                                unsigned char* __restrict__ C8,
                                                const float* __restrict__ att_src,
                                                const float* __restrict__ att_dst,
                                                float* __restrict__ a_src,
                                                float* __restrict__ a_dst,
                                                int M, int N, int gridx) {
    constexpr int BN = NF * 16;
    constexpr int KC = (K % 160 == 0) ? 160 : K;   // 64 -> 64; 320/480 -> 160
    constexpr int NCHK = K / KC;
    constexpr int KS = KC / 32;                    // k-steps per chunk
    __shared__ ushort Bs[BN][KC + 8];

    const int nwg = gridDim.x;
    int bid = blockIdx.x;
    {   // bijective XCD chunk swizzle (m204)
        int q = nwg >> 3, r = nwg & 7;
        int xcd = bid & 7, idx = bid >> 3;
        bid = (xcd < r ? xcd * (q + 1) : r * (q + 1) + (xcd - r) * q) + idx;
    }
    const int by = bid / gridx;          // row panel (64 rows)
    const int bx = bid % gridx;          // col tile == head index
    const int bn = bx * BN;

    const int tid = threadIdx.x;
    const int w = tid >> 6;
    const int lane = tid & 63;
    const int l15 = lane & 15;
    const int lhi = lane >> 4;           // 0..3

    const int bm = by * 64 + w * 16;
    int arow = bm + l15;
    if (arow >= M) arow = M - 1;         // clamp; stores masked
    const ushort* ap = A + (size_t)arow * K + lhi * 8;

    f32x4 acc[NF];
    #pragma unroll
    for (int f = 0; f < NF; ++f) acc[f] = (f32x4){0.f, 0.f, 0.f, 0.f};

    #pragma unroll
    for (int ch = 0; ch < NCHK; ++ch) {
        const int c0 = ch * KC;
        // ---- stage B chunk (BN x KC) into LDS ----
        if (ch > 0) __syncthreads();     // all waves done reading previous chunk
        constexpr int NCH = BN * (KC / 8);
        for (int i = tid; i < NCH; i += 256) {
            int r = i / (KC / 8), c8 = i % (KC / 8);
            short8 v = *(const short8*)(B + (size_t)(bn + r) * K + c0 + c8 * 8);
            *(short8*)(&Bs[r][c8 * 8]) = v;
        }
        __syncthreads();

        short8 a_cur = *(const short8*)(ap + c0);
        short8 b_cur[NF], b_nxt[NF];
        #pragma unroll
        for (int f = 0; f < NF; ++f)
            b_cur[f] = *(const short8*)(&Bs[f * 16 + l15][lhi * 8]);

        #pragma unroll
        for (int ks = 0; ks < KS; ++ks) {
            short8 a_nxt = a_cur;
            if (ks + 1 < KS) {
                a_nxt = *(const short8*)(ap + c0 + (ks + 1) * 32);
                #pragma unroll
                for (int f = 0; f < NF; ++f)
                    b_nxt[f] = *(const short8*)(&Bs[f * 16 + l15][(ks + 1) * 32 + lhi * 8]);
            }
            #pragma unroll
            for (int f = 0; f < NF; ++f)
                acc[f] = __builtin_amdgcn_mfma_f32_16x16x32_bf16(a_cur, b_cur[f], acc[f], 0, 0, 0);
            a_cur = a_nxt;
            #pragma unroll
            for (int f = 0; f < NF; ++f) b_cur[f] = b_nxt[f];
        }
    }

    // ---- C store ----
    #pragma unroll
    for (int f = 0; f < NF; ++f) {
        #pragma unroll
        for (int j = 0; j < 4; ++j) {
            int row = bm + lhi * 4 + j;
            if (row < M) {
                if (F8) C8[(size_t)row * N + bn + f * 16 + l15] = f2f8(acc[f][j]);
                else    C[(size_t)row * N + bn + f * 16 + l15] = f2b(acc[f][j]);
            }
        }
    }

    // ---- fused attention dots (BN == C, head = bx) ----
    float as_v[NF], ad_v[NF];
    #pragma unroll
    for (int f = 0; f < NF; ++f) {
        as_v[f] = att_src[bx * BN + f * 16 + l15];
        ad_v[f] = att_dst[bx * BN + f * 16 + l15];
    }
    #pragma unroll
    for (int j = 0; j < 4; ++j) {
        float ps = 0.f, pd = 0.f;
        #pragma unroll
        for (int f = 0; f < NF; ++f) {
            ps += acc[f][j] * as_v[f];
            pd += acc[f][j] * ad_v[f];
        }
        #pragma unroll
        for (int off = 1; off < 16; off <<= 1) {
            ps += __shfl_xor(ps, off);
            pd += __shfl_xor(pd, off);
        }
        int row = bm + lhi * 4 + j;
        if (l15 == 0 && row < M) {
            a_src[row * H + bx] = ps;
            a_dst[row * H + bx] = pd;
        }
    }
}

// ---------------------------------------------------------------------------
// fp8 GAT aggregate, HEAD-MAJOR flat mapping + XCD chunk swizzle:
// work id t = hd*(N*CH) + n*CH + ck  (CH = C/8 chunks per node-head).
// Each XCD covers a contiguous work range == at most ~2 head slices of h8
// (slice = N*C bytes: 1.28/1.92 MB) -> slice fits its 4 MB L2 -> gathers
// become L2 hits instead of 8x-duplicated HBM fetches.
// ---------------------------------------------------------------------------
template <int H, int C>
__global__ void gat_agg_f8_hm(const unsigned char* __restrict__ h8,
                              const float* __restrict__ a_src, const float* __restrict__ a_dst,
                              const int* __restrict__ row_start, const int* __restrict__ csr_src,
                              const float* __restrict__ bias, ushort* __restrict__ out, int N) {
    constexpr int W = H * C;
    constexpr int CH = C / 8;            // chunks per (node, head): 8 or 12
    const int nwg = gridDim.x;
    int bid = blockIdx.x;
    {   // bijective XCD chunk swizzle (m204)
        int q = nwg >> 3, r = nwg & 7;
        int xcd = bid & 7, idx = bid >> 3;
        bid = (xcd < r ? xcd * (q + 1) : r * (q + 1) + (xcd - r) * q) + idx;
    }
    int t = bid * 256 + (int)threadIdx.x;
    int hd = t / (N * CH);
    if (hd >= H) return;
    int rem = t - hd * (N * CH);
    int n = rem / CH;
    int ck = rem - n * CH;
    int col = hd * CH + ck;              // 8-byte chunk index within full row
    float adst = a_dst[n * H + hd];

    // self loop initializes online state (weight exp(0)=1)
    float m = lrelu(a_src[n * H + hd] + adst);
    float ssum = 1.f;
    f32x2 acc2[4];
    {
        uint2v r = *(const uint2v*)(h8 + (size_t)n * W + 8 * col);
        dec8(r, acc2);
    }

    int rs = row_start[n], re = row_start[n + 1];
    int i = rs;
    for (; i + 8 <= re; i += 8) {
        int s[8]; uint2v r[8]; float e[8];
        #pragma unroll
        for (int j = 0; j < 8; ++j) s[j] = csr_src[i + j];
        #pragma unroll
        for (int j = 0; j < 8; ++j) r[j] = *(const uint2v*)(h8 + (size_t)s[j] * W + 8 * col);
        #pragma unroll
        for (int j = 0; j < 8; ++j) e[j] = lrelu(a_src[s[j] * H + hd] + adst);
        float nm = m;
        #pragma unroll
        for (int j = 0; j < 8; ++j) nm = fmaxf(nm, e[j]);
        float scale = __expf(m - nm);
        m = nm;
        f32x2 sc = {scale, scale};
        #pragma unroll
        for (int d = 0; d < 4; ++d) acc2[d] *= sc;
        ssum *= scale;
        float wsum = 0.f;
        #pragma unroll
        for (int j = 0; j < 8; ++j) {
            float wj = __expf(e[j] - nm);
            wsum += wj;
            f32x2 dd[4];
            dec8(r[j], dd);
            f32x2 vw = {wj, wj};
            #pragma unroll
            for (int d = 0; d < 4; ++d) acc2[d] += vw * dd[d];
        }
        ssum += wsum;
    }
    for (; i < re; ++i) {
        int s = csr_src[i];
        uint2v r = *(const uint2v*)(h8 + (size_t)s * W + 8 * col);
        float e = lrelu(a_src[s * H + hd] + adst);
        float nm = fmaxf(m, e);
        float scale = __expf(m - nm);
        m = nm;
        float wgt = __expf(e - nm);
        ssum = ssum * scale + wgt;
        f32x2 dd[4];
        dec8(r, dd);
        f32x2 sc = {scale, scale};
        f32x2 vw = {wgt, wgt};
        #pragma unroll
        for (int d = 0; d < 4; ++d) acc2[d] = acc2[d] * sc + vw * dd[d];
    }

    float inv = 1.f / (ssum + 1e-16f);
    short8 o;
    #pragma unroll
    for (int d = 0; d < 4; ++d) {
        #pragma unroll
        for (int e2 = 0; e2 < 2; ++e2) {
            float v = acc2[d][e2] * inv + bias[8 * col + 2 * d + e2];
            o[2 * d + e2] = (short)f2b(v > 0.f ? v : 0.f);
        }
    }
    *(short8*)(out + (size_t)n * W + 8 * col) = o;
}

// ---------------------------------------------------------------------------
// Layer-3 aggregate (H=1, C=32, bf16): one wave/node, 16 edge groups x 4
// lanes, online-softmax butterfly merge; bf16 out (no atomics).
// ---------------------------------------------------------------------------
__global__ void gat_agg_c32(const ushort* __restrict__ h, const float* __restrict__ a_src,
                            const float* __restrict__ a_dst, const int* __restrict__ row_start,
                            const int* __restrict__ csr_src, const float* __restrict__ bias,
                            ushort* __restrict__ out, int N) {
    int n = (blockIdx.x * blockDim.x + threadIdx.x) >> 6;
    int lane = threadIdx.x & 63;
    if (n >= N) return;
    int g = lane >> 2;      // edge group 0..15
    int q = lane & 3;       // row chunk: channels [8q, 8q+8)
    float adst = a_dst[n];
    int rs = row_start[n];
    int total = row_start[n + 1] - rs + 1;   // + self loop (k==0)

    float m = -1e30f, ssum = 0.f;
    float acc[8];
    #pragma unroll
    for (int j = 0; j < 8; ++j) acc[j] = 0.f;

    for (int k = g; k < total; k += 16) {
        int s = (k == 0) ? n : csr_src[rs + k - 1];
        float e = lrelu(a_src[s] + adst);
        float nm = fmaxf(m, e);
        float scale = __expf(m - nm);        // m=-1e30 -> 0
        m = nm;
        float w = __expf(e - nm);
        ssum = ssum * scale + w;
        short8 r = *(const short8*)(h + (size_t)s * 32 + 8 * q);
        #pragma unroll
        for (int j = 0; j < 8; ++j) acc[j] = acc[j] * scale + w * b2f((ushort)r[j]);
    }

    #pragma unroll
    for (int off = 4; off < 64; off <<= 1) {
        float m2 = __shfl_xor(m, off);
        float s2 = __shfl_xor(ssum, off);
        float nm = fmaxf(m, m2);
        float sc1 = __expf(m - nm), sc2 = __expf(m2 - nm);
        ssum = ssum * sc1 + s2 * sc2;
        #pragma unroll
        for (int j = 0; j < 8; ++j) {
            float a2 = __shfl_xor(acc[j], off);
            acc[j] = acc[j] * sc1 + a2 * sc2;
        }
        m = nm;
    }

    if (lane < 4) {
        float inv = 1.f / (ssum + 1e-16f);
        short8 o;
        #pragma unroll
        for (int j = 0; j < 8; ++j) {
            float v = acc[j] * inv + bias[8 * lane + j];
            o[j] = (short)f2b(v > 0.f ? v : 0.f);
        }
        *(short8*)(out + (size_t)n * 32 + 8 * lane) = o;
    }
}

// ---------------------------------------------------------------------------
// Fused pool (atomic-free, sorted batch -> binary search) + 2-layer MLP +
// sigmoid. One block (256 thr) per graph.
// ---------------------------------------------------------------------------
__global__ __launch_bounds__(256) void pool_mlp(const ushort* __restrict__ x,
                                                const int* __restrict__ batch,
                                                const float* __restrict__ lin_w,
                                                const float* __restrict__ lin_b,
                                                const float* __restrict__ lin2_w,
                                                const float* __restrict__ lin2_b,
                                                float* __restrict__ outp, int N) {
    int gr = blockIdx.x;
    int a = 0, b = N;
    while (a < b) { int mid = (a + b) >> 1; if (batch[mid] < gr) a = mid + 1; else b = mid; }
    int lo = a;
    b = N;
    while (a < b) { int mid = (a + b) >> 1; if (batch[mid] < gr + 1) a = mid + 1; else b = mid; }
    int hi = a;

    int tid = threadIdx.x;
    int c = tid & 31;        // channel
    int grp = tid >> 5;      // node group 0..7
    float s = 0.f;
    for (int n = lo + grp; n < hi; n += 8)
        s += b2f(x[(size_t)n * 32 + c]);
    __shared__ float sh[8][33];
    __shared__ float grow[32];
    __shared__ float red[4];
    sh[grp][c] = s;
    __syncthreads();
    if (tid < 32) {
        float t = 0.f;
        #pragma unroll
        for (int k = 0; k < 8; ++k) t += sh[k][tid];
        grow[tid] = t;
    }
    __syncthreads();
    float partial = 0.f;
    #pragma unroll
    for (int u = 0; u < 4; ++u) {
        int o = tid + u * 256;
        float s2 = lin_b[o];
        const float* wp = lin_w + (size_t)o * 32;
        #pragma unroll
        for (int k = 0; k < 32; ++k) s2 += grow[k] * wp[k];
        s2 = s2 > 0.f ? s2 : 0.f;
        partial += s2 * lin2_w[o];
    }
    #pragma unroll
    for (int off = 32; off; off >>= 1) partial += __shfl_down(partial, off);
    int lane = tid & 63, wv = tid >> 6;
    if (lane == 0) red[wv] = partial;
    __syncthreads();
    if (tid == 0) {
        float t = red[0] + red[1] + red[2] + red[3] + lin2_b[0];
        outp[gr] = 1.f / (1.f + expf(-t));
    }
}

// ---------------------------------------------------------------------------
static inline size_t al256(size_t x) { return (x + 255) & ~(size_t)255; }

extern "C" void kernel_launch(void* const* d_in, const int* in_sizes, int n_in,
                              void* d_out, int out_size, void* d_ws, size_t ws_size,
                              hipStream_t stream) {
    const float* x      = (const float*)d_in[0];
    const float* W1     = (const float*)d_in[1];
    const float* as1    = (const float*)d_in[2];
    const float* ad1    = (const float*)d_in[3];
    const float* b1     = (const float*)d_in[4];
    const float* W2     = (const float*)d_in[5];
    const float* as2    = (const float*)d_in[6];
    const float* ad2    = (const float*)d_in[7];
    const float* b2     = (const float*)d_in[8];
    const float* W3     = (const float*)d_in[9];
    const float* as3    = (const float*)d_in[10];
    const float* ad3    = (const float*)d_in[11];
    const float* b3     = (const float*)d_in[12];
    const float* lin_w  = (const float*)d_in[13];
    const float* lin_b  = (const float*)d_in[14];
    const float* lin2_w = (const float*)d_in[15];
    const float* lin2_b = (const float*)d_in[16];
    const int*   ei     = (const int*)d_in[17];
    const int*   batch  = (const int*)d_in[18];
    float* outp = (float*)d_out;

    const int E = in_sizes[17] / 2;
    const int* e_src = ei;
    const int* e_dst = ei + E;

    // workspace carve-up
    char* p = (char*)d_ws;
    ushort* h_bf   = (ushort*)p; p += al256((size_t)NN * 480 * 2);
    ushort* o_bf   = (ushort*)p; p += al256((size_t)NN * 480 * 2);
    unsigned char* h_f8 = (unsigned char*)p; p += al256((size_t)NN * 480);
    ushort* x_bf   = (ushort*)p; p += al256((size_t)NN * 64 * 2);
    ushort* w1_bf  = (ushort*)p; p += al256((size_t)320 * 64 * 2);
    ushort* w2_bf  = (ushort*)p; p += al256((size_t)480 * 320 * 2);
    ushort* w3_bf  = (ushort*)p; p += al256((size_t)32 * 480 * 2);
    float* asrc    = (float*)p; p += al256((size_t)NN * 5 * 4);
    float* adst    = (float*)p; p += al256((size_t)NN * 5 * 4);
    int*   row_st  = (int*)p;   p += al256((size_t)(NN + 1) * 4);
    int*   cnt     = (int*)p;   p += (size_t)NN * 4;          // cnt+cursor adjacent,
    int*   cursor  = (int*)p;   p += (size_t)NN * 4;          // one memset covers both
    p = (char*)al256((size_t)p);
    int*   csr_src = (int*)p;   p += al256((size_t)NE * 4);
    (void)ws_size; (void)n_in; (void)out_size;

    dim3 blk(256);

    // ---- memset (cnt+cursor) then fused converts + edge counting ----
    hipMemsetAsync(cnt, 0, (size_t)2 * NN * 4, stream);
    {
        int tot = CVT_TOT > NE ? CVT_TOT : NE;
        cvt_count_kernel<<<(tot + 255) / 256, blk, 0, stream>>>(
            x, x_bf, W1, w1_bf, W2, w2_bf, W3, w3_bf, e_dst, cnt, E);
    }
    scan_kernel<<<1, 1024, 0, stream>>>(cnt, row_st, NN);
    fill_kernel<<<(E + 255) / 256, 256, 0, stream>>>(e_src, e_dst, row_st, cursor, csr_src, E);

    const int MPAN = (NN + 63) / 64;     // 313 row panels
    const int NBLK = (NN + 3) / 4;       // wave-per-node aggregate (layer 3)
    // ---- layer 1: K=64 -> H=5, C=64 (width 320); fp8 h + fused dots ----
    {
        gemm_lds<64, 4, 5, true><<<5 * MPAN, blk, 0, stream>>>(x_bf, w1_bf, h_bf, h_f8, as1, ad1, asrc, adst, NN, 320, 5);
        int tthr = 5 * NN * 8;           // head-major: H * N * CH, CH = 8
        gat_agg_f8_hm<5, 64><<<(tthr + 255) / 256, blk, 0, stream>>>(h_f8, asrc, adst, row_st, csr_src, b1, o_bf, NN);
    }
    // ---- layer 2: K=320 -> H=5, C=96 (width 480); fp8 h + fused dots ----
    {
        gemm_lds<320, 6, 5, true><<<5 * MPAN, blk, 0, stream>>>(o_bf, w2_bf, h_bf, h_f8, as2, ad2, asrc, adst, NN, 480, 5);
        int tthr = 5 * NN * 12;          // head-major: H * N * CH, CH = 12
        gat_agg_f8_hm<5, 96><<<(tthr + 255) / 256, blk, 0, stream>>>(h_f8, asrc, adst, row_st, csr_src, b2, o_bf, NN);
    }
    // ---- layer 3: K=480 -> H=1, C=32; bf16 h + fused dots ----
    {
        gemm_lds<480, 2, 1, false><<<1 * MPAN, blk, 0, stream>>>(o_bf, w3_bf, h_bf, h_f8, as3, ad3, asrc, adst, NN, 32, 1);
        gat_agg_c32<<<NBLK, blk, 0, stream>>>(h_bf, asrc, adst, row_st, csr_src, b3, o_bf, NN);
    }
    // ---- fused pool + MLP ----
    pool_mlp<<<NG, blk, 0, stream>>>(o_bf, batch, lin_w, lin_b, lin2_w, lin2_b, outp, NN);
}

// Round 14
// 188.218 us; speedup vs baseline: 1.0894x; 1.0894x over previous
//
#include <hip/hip_runtime.h>
#include <math.h>

#define NN 20000
#define NE 320000
#define NG 128

typedef short short8 __attribute__((ext_vector_type(8)));
typedef float f32x4 __attribute__((ext_vector_type(4)));
typedef float f32x2 __attribute__((ext_vector_type(2)));
typedef unsigned short ushort;
typedef unsigned short ushort4v __attribute__((ext_vector_type(4)));
typedef float float4v __attribute__((ext_vector_type(4)));
typedef unsigned int uint;
typedef unsigned int uint2v __attribute__((ext_vector_type(2)));

__device__ __forceinline__ float b2f(ushort u) {
    unsigned int v = ((unsigned int)u) << 16;
    return __uint_as_float(v);
}
__device__ __forceinline__ ushort f2b(float f) {
    unsigned int u = __float_as_uint(f);
    u = (u + 0x7fff + ((u >> 16) & 1)) >> 16;   // RNE
    return (ushort)u;
}
__device__ __forceinline__ float lrelu(float x) { return x >= 0.f ? x : 0.2f * x; }
__device__ __forceinline__ unsigned char f2f8(float v) {
    return (unsigned char)(__builtin_amdgcn_cvt_pk_fp8_f32(v, v, 0, false) & 0xff);
}
// decode 8 fp8 bytes (uint2v) -> 4 packed f32x2 (literal word selects)
__device__ __forceinline__ void dec8(uint2v r, f32x2 d[4]) {
    d[0] = __builtin_amdgcn_cvt_pk_f32_fp8(r.x, false);
    d[1] = __builtin_amdgcn_cvt_pk_f32_fp8(r.x, true);
    d[2] = __builtin_amdgcn_cvt_pk_f32_fp8(r.y, false);
    d[3] = __builtin_amdgcn_cvt_pk_f32_fp8(r.y, true);
}

// ---------------------------------------------------------------------------
// fused f32->bf16 convert of x, W1, W2, W3 + edge-dst counting (one launch)
// ---------------------------------------------------------------------------
#define CVT_N0 (NN * 64 / 4)
#define CVT_N1 (320 * 64 / 4)
#define CVT_N2 (480 * 320 / 4)
#define CVT_N3 (32 * 480 / 4)
#define CVT_TOT (CVT_N0 + CVT_N1 + CVT_N2 + CVT_N3)
__global__ void cvt_count_kernel(const float* __restrict__ a0, ushort* __restrict__ o0,
                                 const float* __restrict__ a1, ushort* __restrict__ o1,
                                 const float* __restrict__ a2, ushort* __restrict__ o2,
                                 const float* __restrict__ a3, ushort* __restrict__ o3,
                                 const int* __restrict__ e_dst, int* __restrict__ cnt, int E) {
    int i = blockIdx.x * blockDim.x + threadIdx.x;
    if (i < E) atomicAdd(&cnt[e_dst[i]], 1);
    const float* src; ushort* dst; int li;
    if (i < CVT_N0) { src = a0; dst = o0; li = i; }
    else if (i < CVT_N0 + CVT_N1) { src = a1; dst = o1; li = i - CVT_N0; }
    else if (i < CVT_N0 + CVT_N1 + CVT_N2) { src = a2; dst = o2; li = i - CVT_N0 - CVT_N1; }
    else if (i < CVT_TOT) { src = a3; dst = o3; li = i - CVT_N0 - CVT_N1 - CVT_N2; }
    else return;
    float4v v = *(const float4v*)(src + (size_t)li * 4);
    ushort4v r;
    r.x = f2b(v.x); r.y = f2b(v.y); r.z = f2b(v.z); r.w = f2b(v.w);
    *(ushort4v*)(dst + (size_t)li * 4) = r;
}

// ---------------------------------------------------------------------------
// CSR build: (count fused above) -> parallel scan -> fill
// ---------------------------------------------------------------------------
__global__ __launch_bounds__(1024) void scan_kernel(const int* __restrict__ cnt,
                                                    int* __restrict__ row_start, int n) {
    __shared__ int sh[1024];
    int tid = threadIdx.x;
    int base = tid * 20;
    int local[20];
    int s = 0;
    #pragma unroll
    for (int k = 0; k < 20; ++k) {
        int idx = base + k;
        int v = (idx < n) ? cnt[idx] : 0;
        local[k] = s;           // exclusive within chunk
        s += v;
    }
    sh[tid] = s;
    __syncthreads();
    for (int off = 1; off < 1024; off <<= 1) {
        int t = (tid >= off) ? sh[tid - off] : 0;
        __syncthreads();
        sh[tid] += t;
        __syncthreads();
    }
    int pre = (tid == 0) ? 0 : sh[tid - 1];
    #pragma unroll
    for (int k = 0; k < 20; ++k) {
        int idx = base + k;
        if (idx < n) row_start[idx] = pre + local[k];
    }
    if (tid == 1023) row_start[n] = sh[1023];
}

__global__ void fill_kernel(const int* __restrict__ src, const int* __restrict__ dst,
                            const int* __restrict__ row_start, int* __restrict__ cursor,
                            int* __restrict__ csr_src, int E) {
    int i = blockIdx.x * blockDim.x + threadIdx.x;
    if (i < E) {
        int d = dst[i];
        int pos = atomicAdd(&cursor[d], 1);
        csr_src[row_start[d] + pos] = src[i];
    }
}

// ---------------------------------------------------------------------------
// MFMA GEMM, K-chunked LDS staging (chunk KC<=160 -> small LDS, high occ) +
// reg double-buffering + FUSED per-head attention dots (BN == C, head = bx).
// F8 variant stores C as fp8 e4m3 bytes (direct from f32 acc).
// ---------------------------------------------------------------------------
template <int K, int NF, int H, bool F8>
__global__ __launch_bounds__(256) void gemm_lds(const ushort* __restrict__ A,
                                                const ushort* __restrict__ B,
                                                ushort* __restrict__ C,
                                                unsigned char* __restrict__ C8,
                                                const float* __restrict__ att_src,
                                                const float* __restrict__ att_dst,
                                                float* __restrict__ a_src,
                                                float* __restrict__ a_dst,
                                                int M, int N, int gridx) {
    constexpr int BN = NF * 16;
    constexpr int KC = (K % 160 == 0) ? 160 : K;   // 64 -> 64; 320/480 -> 160
    constexpr int NCHK = K / KC;
    constexpr int KS = KC / 32;                    // k-steps per chunk
    __shared__ ushort Bs[BN][KC + 8];

    const int nwg = gridDim.x;
    int bid = blockIdx.x;
    {   // bijective XCD chunk swizzle (m204)
        int q = nwg >> 3, r = nwg & 7;
        int xcd = bid & 7, idx = bid >> 3;
        bid = (xcd < r ? xcd * (q + 1) : r * (q + 1) + (xcd - r) * q) + idx;
    }
    const int by = bid / gridx;          // row panel (64 rows)
    const int bx = bid % gridx;          // col tile == head index
    const int bn = bx * BN;

    const int tid = threadIdx.x;
    const int w = tid >> 6;
    const int lane = tid & 63;
    const int l15 = lane & 15;
    const int lhi = lane >> 4;           // 0..3

    const int bm = by * 64 + w * 16;
    int arow = bm + l15;
    if (arow >= M) arow = M - 1;         // clamp; stores masked
    const ushort* ap = A + (size_t)arow * K + lhi * 8;

    f32x4 acc[NF];
    #pragma unroll
    for (int f = 0; f < NF; ++f) acc[f] = (f32x4){0.f, 0.f, 0.f, 0.f};

    #pragma unroll
    for (int ch = 0; ch < NCHK; ++ch) {
        const int c0 = ch * KC;
        // ---- stage B chunk (BN x KC) into LDS ----
        if (ch > 0) __syncthreads();     // all waves done reading previous chunk
        constexpr int NCH = BN * (KC / 8);
        for (int i = tid; i < NCH; i += 256) {
            int r = i / (KC / 8), c8 = i % (KC / 8);
            short8 v = *(const short8*)(B + (size_t)(bn + r) * K + c0 + c8 * 8);
            *(short8*)(&Bs[r][c8 * 8]) = v;
        }
        __syncthreads();

        short8 a_cur = *(const short8*)(ap + c0);
        short8 b_cur[NF], b_nxt[NF];
        #pragma unroll
        for (int f = 0; f < NF; ++f)
            b_cur[f] = *(const short8*)(&Bs[f * 16 + l15][lhi * 8]);

        #pragma unroll
        for (int ks = 0; ks < KS; ++ks) {
            short8 a_nxt = a_cur;
            if (ks + 1 < KS) {
                a_nxt = *(const short8*)(ap + c0 + (ks + 1) * 32);
                #pragma unroll
                for (int f = 0; f < NF; ++f)
                    b_nxt[f] = *(const short8*)(&Bs[f * 16 + l15][(ks + 1) * 32 + lhi * 8]);
            }
            #pragma unroll
            for (int f = 0; f < NF; ++f)
                acc[f] = __builtin_amdgcn_mfma_f32_16x16x32_bf16(a_cur, b_cur[f], acc[f], 0, 0, 0);
            a_cur = a_nxt;
            #pragma unroll
            for (int f = 0; f < NF; ++f) b_cur[f] = b_nxt[f];
        }
    }

    // ---- C store ----
    #pragma unroll
    for (int f = 0; f < NF; ++f) {
        #pragma unroll
        for (int j = 0; j < 4; ++j) {
            int row = bm + lhi * 4 + j;
            if (row < M) {
                if (F8) C8[(size_t)row * N + bn + f * 16 + l15] = f2f8(acc[f][j]);
                else    C[(size_t)row * N + bn + f * 16 + l15] = f2b(acc[f][j]);
            }
        }
    }

    // ---- fused attention dots (BN == C, head = bx) ----
    float as_v[NF], ad_v[NF];
    #pragma unroll
    for (int f = 0; f < NF; ++f) {
        as_v[f] = att_src[bx * BN + f * 16 + l15];
        ad_v[f] = att_dst[bx * BN + f * 16 + l15];
    }
    #pragma unroll
    for (int j = 0; j < 4; ++j) {
        float ps = 0.f, pd = 0.f;
        #pragma unroll
        for (int f = 0; f < NF; ++f) {
            ps += acc[f][j] * as_v[f];
            pd += acc[f][j] * ad_v[f];
        }
        #pragma unroll
        for (int off = 1; off < 16; off <<= 1) {
            ps += __shfl_xor(ps, off);
            pd += __shfl_xor(pd, off);
        }
        int row = bm + lhi * 4 + j;
        if (l15 == 0 && row < M) {
            a_src[row * H + bx] = ps;
            a_dst[row * H + bx] = pd;
        }
    }
}

// ---------------------------------------------------------------------------
// fp8 GAT aggregate, FLAT mapping (layer 1, W=320): thread t -> node t/40,
// chunk t%40. DEFER-MAX: softmax shift m updated only when tile max exceeds
// m+8 (exp(e-m) <= e^8, exact math -- softmax is shift-invariant).
// ---------------------------------------------------------------------------
template <int H, int C>
__global__ void gat_agg_f8_flat(const unsigned char* __restrict__ h8,
                                const float* __restrict__ a_src, const float* __restrict__ a_dst,
                                const int* __restrict__ row_start, const int* __restrict__ csr_src,
                                const float* __restrict__ bias, ushort* __restrict__ out, int N) {
    constexpr int W = H * C;
    constexpr int NCHK = W / 8;      // chunks per node (40)
    int t = blockIdx.x * blockDim.x + threadIdx.x;
    int n = t / NCHK;
    int l = t % NCHK;
    if (n >= N) return;
    int hd = (8 * l) / C;
    float adst = a_dst[n * H + hd];

    float m = lrelu(a_src[n * H + hd] + adst);
    float ssum = 1.f;
    f32x2 acc2[4];
    {
        uint2v r = *(const uint2v*)(h8 + (size_t)n * W + 8 * l);
        dec8(r, acc2);
    }

    int rs = row_start[n], re = row_start[n + 1];
    int i = rs;
    for (; i + 8 <= re; i += 8) {
        int s[8]; uint2v r[8]; float e[8];
        #pragma unroll
        for (int j = 0; j < 8; ++j) s[j] = csr_src[i + j];
        #pragma unroll
        for (int j = 0; j < 8; ++j) r[j] = *(const uint2v*)(h8 + (size_t)s[j] * W + 8 * l);
        #pragma unroll
        for (int j = 0; j < 8; ++j) e[j] = lrelu(a_src[s[j] * H + hd] + adst);
        float nm = m;
        #pragma unroll
        for (int j = 0; j < 8; ++j) nm = fmaxf(nm, e[j]);
        if (nm > m + 8.f) {              // rare rescale (defer-max)
            float scale = __expf(m - nm);
            f32x2 sc = {scale, scale};
            #pragma unroll
            for (int d = 0; d < 4; ++d) acc2[d] *= sc;
            ssum *= scale;
            m = nm;
        }
        float wsum = 0.f;
        #pragma unroll
        for (int j = 0; j < 8; ++j) {
            float wj = __expf(e[j] - m);
            wsum += wj;
            f32x2 dd[4];
            dec8(r[j], dd);
            f32x2 vw = {wj, wj};
            #pragma unroll
            for (int d = 0; d < 4; ++d) acc2[d] += vw * dd[d];
        }
        ssum += wsum;
    }
    for (; i < re; ++i) {
        int s = csr_src[i];
        uint2v r = *(const uint2v*)(h8 + (size_t)s * W + 8 * l);
        float e = lrelu(a_src[s * H + hd] + adst);
        if (e > m + 8.f) {
            float scale = __expf(m - e);
            f32x2 sc = {scale, scale};
            #pragma unroll
            for (int d = 0; d < 4; ++d) acc2[d] *= sc;
            ssum *= scale;
            m = e;
        }
        float wgt = __expf(e - m);
        ssum += wgt;
        f32x2 dd[4];
        dec8(r, dd);
        f32x2 vw = {wgt, wgt};
        #pragma unroll
        for (int d = 0; d < 4; ++d) acc2[d] += vw * dd[d];
    }

    float inv = 1.f / (ssum + 1e-16f);
    short8 o;
    #pragma unroll
    for (int d = 0; d < 4; ++d) {
        #pragma unroll
        for (int e2 = 0; e2 < 2; ++e2) {
            float v = acc2[d][e2] * inv + bias[8 * l + 2 * d + e2];
            o[2 * d + e2] = (short)f2b(v > 0.f ? v : 0.f);
        }
    }
    *(short8*)(out + (size_t)n * W + 8 * l) = o;
}

// ---------------------------------------------------------------------------
// fp8 GAT aggregate, wave-per-node (layer 2, W=480 -> 60/64 lanes), defer-max.
// ---------------------------------------------------------------------------
template <int H, int C>
__global__ void gat_agg_f8(const unsigned char* __restrict__ h8,
                           const float* __restrict__ a_src, const float* __restrict__ a_dst,
                           const int* __restrict__ row_start, const int* __restrict__ csr_src,
                           const float* __restrict__ bias, ushort* __restrict__ out, int N) {
    constexpr int W = H * C;
    constexpr int VL = W / 8;        // active lanes (60)
    int n = (blockIdx.x * blockDim.x + threadIdx.x) >> 6;
    int lane = threadIdx.x & 63;
    if (n >= N) return;
    bool act = lane < VL;
    int l = act ? lane : 0;
    int hd = (8 * l) / C;
    float adst = a_dst[n * H + hd];

    float m = lrelu(a_src[n * H + hd] + adst);
    float ssum = 1.f;
    f32x2 acc2[4];
    {
        uint2v r = *(const uint2v*)(h8 + (size_t)n * W + 8 * l);
        dec8(r, acc2);
    }

    int rs = row_start[n], re = row_start[n + 1];
    int i = rs;
    for (; i + 8 <= re; i += 8) {
        int s[8]; uint2v r[8]; float e[8];
        #pragma unroll
        for (int j = 0; j < 8; ++j) s[j] = csr_src[i + j];
        #pragma unroll
        for (int j = 0; j < 8; ++j) r[j] = *(const uint2v*)(h8 + (size_t)s[j] * W + 8 * l);
        #pragma unroll
        for (int j = 0; j < 8; ++j) e[j] = lrelu(a_src[s[j] * H + hd] + adst);
        float nm = m;
        #pragma unroll
        for (int j = 0; j < 8; ++j) nm = fmaxf(nm, e[j]);
        if (nm > m + 8.f) {              // rare rescale (defer-max)
            float scale = __expf(m - nm);
            f32x2 sc = {scale, scale};
            #pragma unroll
            for (int d = 0; d < 4; ++d) acc2[d] *= sc;
            ssum *= scale;
            m = nm;
        }
        float wsum = 0.f;
        #pragma unroll
        for (int j = 0; j < 8; ++j) {
            float wj = __expf(e[j] - m);
            wsum += wj;
            f32x2 dd[4];
            dec8(r[j], dd);
            f32x2 vw = {wj, wj};
            #pragma unroll
            for (int d = 0; d < 4; ++d) acc2[d] += vw * dd[d];
        }
        ssum += wsum;
    }
    for (; i < re; ++i) {
        int s = csr_src[i];
        uint2v r = *(const uint2v*)(h8 + (size_t)s * W + 8 * l);
        float e = lrelu(a_src[s * H + hd] + adst);
        if (e > m + 8.f) {
            float scale = __expf(m - e);
            f32x2 sc = {scale, scale};
            #pragma unroll
            for (int d = 0; d < 4; ++d) acc2[d] *= sc;
            ssum *= scale;
            m = e;
        }
        float wgt = __expf(e - m);
        ssum += wgt;
        f32x2 dd[4];
        dec8(r, dd);
        f32x2 vw = {wgt, wgt};
        #pragma unroll
        for (int d = 0; d < 4; ++d) acc2[d] += vw * dd[d];
    }

    float inv = 1.f / (ssum + 1e-16f);
    if (act) {
        short8 o;
        #pragma unroll
        for (int d = 0; d < 4; ++d) {
            #pragma unroll
            for (int e2 = 0; e2 < 2; ++e2) {
                float v = acc2[d][e2] * inv + bias[8 * l + 2 * d + e2];
                o[2 * d + e2] = (short)f2b(v > 0.f ? v : 0.f);
            }
        }
        *(short8*)(out + (size_t)n * W + 8 * l) = o;
    }
}

// ---------------------------------------------------------------------------
// Layer-3 aggregate (H=1, C=32, bf16): one wave/node, 16 edge groups x 4
// lanes, online-softmax butterfly merge; bf16 out (no atomics).
// ---------------------------------------------------------------------------
__global__ void gat_agg_c32(const ushort* __restrict__ h, const float* __restrict__ a_src,
                            const float* __restrict__ a_dst, const int* __restrict__ row_start,
                            const int* __restrict__ csr_src, const float* __restrict__ bias,
                            ushort* __restrict__ out, int N) {
    int n = (blockIdx.x * blockDim.x + threadIdx.x) >> 6;
    int lane = threadIdx.x & 63;
    if (n >= N) return;
    int g = lane >> 2;      // edge group 0..15
    int q = lane & 3;       // row chunk: channels [8q, 8q+8)
    float adst = a_dst[n];
    int rs = row_start[n];
    int total = row_start[n + 1] - rs + 1;   // + self loop (k==0)

    float m = -1e30f, ssum = 0.f;
    float acc[8];
    #pragma unroll
    for (int j = 0; j < 8; ++j) acc[j] = 0.f;

    for (int k = g; k < total; k += 16) {
        int s = (k == 0) ? n : csr_src[rs + k - 1];
        float e = lrelu(a_src[s] + adst);
        float nm = fmaxf(m, e);
        float scale = __expf(m - nm);        // m=-1e30 -> 0
        m = nm;
        float w = __expf(e - nm);
        ssum = ssum * scale + w;
        short8 r = *(const short8*)(h + (size_t)s * 32 + 8 * q);
        #pragma unroll
        for (int j = 0; j < 8; ++j) acc[j] = acc[j] * scale + w * b2f((ushort)r[j]);
    }

    #pragma unroll
    for (int off = 4; off < 64; off <<= 1) {
        float m2 = __shfl_xor(m, off);
        float s2 = __shfl_xor(ssum, off);
        float nm = fmaxf(m, m2);
        float sc1 = __expf(m - nm), sc2 = __expf(m2 - nm);
        ssum = ssum * sc1 + s2 * sc2;
        #pragma unroll
        for (int j = 0; j < 8; ++j) {
            float a2 = __shfl_xor(acc[j], off);
            acc[j] = acc[j] * sc1 + a2 * sc2;
        }
        m = nm;
    }

    if (lane < 4) {
        float inv = 1.f / (ssum + 1e-16f);
        short8 o;
        #pragma unroll
        for (int j = 0; j < 8; ++j) {
            float v = acc[j] * inv + bias[8 * lane + j];
            o[j] = (short)f2b(v > 0.f ? v : 0.f);
        }
        *(short8*)(out + (size_t)n * 32 + 8 * lane) = o;
    }
}

// ---------------------------------------------------------------------------
// Fused pool (atomic-free, sorted batch -> binary search) + 2-layer MLP +
// sigmoid. One block (256 thr) per graph.
// ---------------------------------------------------------------------------
__global__ __launch_bounds__(256) void pool_mlp(const ushort* __restrict__ x,
                                                const int* __restrict__ batch,
                                                const float* __restrict__ lin_w,
                                                const float* __restrict__ lin_b,
                                                const float* __restrict__ lin2_w,
                                                const float* __restrict__ lin2_b,
                                                float* __restrict__ outp, int N) {
    int gr = blockIdx.x;
    int a = 0, b = N;
    while (a < b) { int mid = (a + b) >> 1; if (batch[mid] < gr) a = mid + 1; else b = mid; }
    int lo = a;
    b = N;
    while (a < b) { int mid = (a + b) >> 1; if (batch[mid] < gr + 1) a = mid + 1; else b = mid; }
    int hi = a;

    int tid = threadIdx.x;
    int c = tid & 31;        // channel
    int grp = tid >> 5;      // node group 0..7
    float s = 0.f;
    for (int n = lo + grp; n < hi; n += 8)
        s += b2f(x[(size_t)n * 32 + c]);
    __shared__ float sh[8][33];
    __shared__ float grow[32];
    __shared__ float red[4];
    sh[grp][c] = s;
    __syncthreads();
    if (tid < 32) {
        float t = 0.f;
        #pragma unroll
        for (int k = 0; k < 8; ++k) t += sh[k][tid];
        grow[tid] = t;
    }
    __syncthreads();
    float partial = 0.f;
    #pragma unroll
    for (int u = 0; u < 4; ++u) {
        int o = tid + u * 256;
        float s2 = lin_b[o];
        const float* wp = lin_w + (size_t)o * 32;
        #pragma unroll
        for (int k = 0; k < 32; ++k) s2 += grow[k] * wp[k];
        s2 = s2 > 0.f ? s2 : 0.f;
        partial += s2 * lin2_w[o];
    }
    #pragma unroll
    for (int off = 32; off; off >>= 1) partial += __shfl_down(partial, off);
    int lane = tid & 63, wv = tid >> 6;
    if (lane == 0) red[wv] = partial;
    __syncthreads();
    if (tid == 0) {
        float t = red[0] + red[1] + red[2] + red[3] + lin2_b[0];
        outp[gr] = 1.f / (1.f + expf(-t));
    }
}

// ---------------------------------------------------------------------------
static inline size_t al256(size_t x) { return (x + 255) & ~(size_t)255; }

extern "C" void kernel_launch(void* const* d_in, const int* in_sizes, int n_in,
                              void* d_out, int out_size, void* d_ws, size_t ws_size,
                              hipStream_t stream) {
    const float* x      = (const float*)d_in[0];
    const float* W1     = (const float*)d_in[1];
    const float* as1    = (const float*)d_in[2];
    const float* ad1    = (const float*)d_in[3];
    const float* b1     = (const float*)d_in[4];
    const float* W2     = (const float*)d_in[5];
    const float* as2    = (const float*)d_in[6];
    const float* ad2    = (const float*)d_in[7];
    const float* b2     = (const float*)d_in[8];
    const float* W3     = (const float*)d_in[9];
    const float* as3    = (const float*)d_in[10];
    const float* ad3    = (const float*)d_in[11];
    const float* b3     = (const float*)d_in[12];
    const float* lin_w  = (const float*)d_in[13];
    const float* lin_b  = (const float*)d_in[14];
    const float* lin2_w = (const float*)d_in[15];
    const float* lin2_b = (const float*)d_in[16];
    const int*   ei     = (const int*)d_in[17];
    const int*   batch  = (const int*)d_in[18];
    float* outp = (float*)d_out;

    const int E = in_sizes[17] / 2;
    const int* e_src = ei;
    const int* e_dst = ei + E;

    // workspace carve-up
    char* p = (char*)d_ws;
    ushort* h_bf   = (ushort*)p; p += al256((size_t)NN * 480 * 2);
    ushort* o_bf   = (ushort*)p; p += al256((size_t)NN * 480 * 2);
    unsigned char* h_f8 = (unsigned char*)p; p += al256((size_t)NN * 480);
    ushort* x_bf   = (ushort*)p; p += al256((size_t)NN * 64 * 2);
    ushort* w1_bf  = (ushort*)p; p += al256((size_t)320 * 64 * 2);
    ushort* w2_bf  = (ushort*)p; p += al256((size_t)480 * 320 * 2);
    ushort* w3_bf  = (ushort*)p; p += al256((size_t)32 * 480 * 2);
    float* asrc    = (float*)p; p += al256((size_t)NN * 5 * 4);
    float* adst    = (float*)p; p += al256((size_t)NN * 5 * 4);
    int*   row_st  = (int*)p;   p += al256((size_t)(NN + 1) * 4);
    int*   cnt     = (int*)p;   p += (size_t)NN * 4;          // cnt+cursor adjacent,
    int*   cursor  = (int*)p;   p += (size_t)NN * 4;          // one memset covers both
    p = (char*)al256((size_t)p);
    int*   csr_src = (int*)p;   p += al256((size_t)NE * 4);
    (void)ws_size; (void)n_in; (void)out_size;

    dim3 blk(256);

    // ---- memset (cnt+cursor) then fused converts + edge counting ----
    hipMemsetAsync(cnt, 0, (size_t)2 * NN * 4, stream);
    {
        int tot = CVT_TOT > NE ? CVT_TOT : NE;
        cvt_count_kernel<<<(tot + 255) / 256, blk, 0, stream>>>(
            x, x_bf, W1, w1_bf, W2, w2_bf, W3, w3_bf, e_dst, cnt, E);
    }
    scan_kernel<<<1, 1024, 0, stream>>>(cnt, row_st, NN);
    fill_kernel<<<(E + 255) / 256, 256, 0, stream>>>(e_src, e_dst, row_st, cursor, csr_src, E);

    const int MPAN = (NN + 63) / 64;     // 313 row panels
    const int NBLK = (NN + 3) / 4;       // wave-per-node aggregates
    // ---- layer 1: K=64 -> H=5, C=64 (width 320); fp8 h + fused dots ----
    {
        gemm_lds<64, 4, 5, true><<<5 * MPAN, blk, 0, stream>>>(x_bf, w1_bf, h_bf, h_f8, as1, ad1, asrc, adst, NN, 320, 5);
        int tthr = NN * 40;              // flat: 40 chunks per node
        gat_agg_f8_flat<5, 64><<<(tthr + 255) / 256, blk, 0, stream>>>(h_f8, asrc, adst, row_st, csr_src, b1, o_bf, NN);
    }
    // ---- layer 2: K=320 -> H=5, C=96 (width 480); fp8 h + fused dots ----
    {
        gemm_lds<320, 6, 5, true><<<5 * MPAN, blk, 0, stream>>>(o_bf, w2_bf, h_bf, h_f8, as2, ad2, asrc, adst, NN, 480, 5);
        gat_agg_f8<5, 96><<<NBLK, blk, 0, stream>>>(h_f8, asrc, adst, row_st, csr_src, b2, o_bf, NN);
    }
    // ---- layer 3: K=480 -> H=1, C=32; bf16 h + fused dots ----
    {
        gemm_lds<480, 2, 1, false><<<1 * MPAN, blk, 0, stream>>>(o_bf, w3_bf, h_bf, h_f8, as3, ad3, asrc, adst, NN, 32, 1);
        gat_agg_c32<<<NBLK, blk, 0, stream>>>(h_bf, asrc, adst, row_st, csr_src, b3, o_bf, NN);
    }
    // ---- fused pool + MLP ----
    pool_mlp<<<NG, blk, 0, stream>>>(o_bf, batch, lin_w, lin_b, lin2_w, lin2_b, outp, NN);
}